// Round 1
// baseline (1153.837 us; speedup 1.0000x reference)
//
#include <hip/hip_runtime.h>

#define BB 16
#define NN 8192
#define SS 512
#define N3 (3 * NN)  // 24576 elements per batch per tensor
#define KD 14        // per-lane KNN list depth (see k_knn comment)

typedef unsigned short u16;
typedef unsigned int u32;
typedef unsigned long long u64;
typedef float v2f __attribute__((ext_vector_type(2)));

// Packed fp32 ops (VOP3P, 2 points/inst). Per-half rounding is IEEE rn —
// bit-identical to scalar __fadd_rn/__fmul_rn.
__device__ __forceinline__ v2f pk_add(v2f a, v2f b) {
  v2f r;
  asm("v_pk_add_f32 %0, %1, %2" : "=v"(r) : "v"(a), "v"(b));
  return r;
}
__device__ __forceinline__ v2f pk_mul(v2f a, v2f b) {
  v2f r;
  asm("v_pk_mul_f32 %0, %1, %2" : "=v"(r) : "v"(a), "v"(b));
  return r;
}

template <int CTRL>
__device__ __forceinline__ float dpp_maxf(float x) {
  // old=0 is the identity for max of non-negative values
  int m = __builtin_amdgcn_update_dpp(0, __float_as_int(x), CTRL, 0xf, 0xf, false);
  return fmaxf(x, __int_as_float(m));
}
template <int CTRL>
__device__ __forceinline__ u32 dpp_maxu(u32 x) {
  u32 m = (u32)__builtin_amdgcn_update_dpp(0, (int)x, CTRL, 0xf, 0xf, false);
  return (x > m) ? x : m;
}

// ---------------------------------------------------------------------------
// K1: farthest point sampling, fp32, bit-exact vs numpy. r14: r13's structure
// scaled from 256 thr (1 wave/SIMD, zero TLP — rocprof showed VALUBusy at only
// ~57% of the 16 active CUs, rest = DPP-chain + LDS-broadcast + barrier
// stalls) to 1024 thr = 16 waves = 4 waves/SIMD. Per-CU VALU work is fixed
// (8192 pts/batch on ONE CU); TLP hides the dependent-chain stalls. Each
// thread owns 8 points (4 v2f). Per wave: value DPP max -> readlane(63) =
// WAVE max -> find pass (bit-equality vs wave max, 4 inst/j, no coord
// tracking) -> cand DPP max -> lane63 writes ONE packed u64
// (dist<<32 | NN-idx) to rkey[parity][wave] -> ONE barrier -> 16-key block
// reduce: each lane loads rkey[lane&15] (conflict-free, 4-way broadcast
// groups) + 4-step shfl_xor u64-max butterfly (every 16-lane group holds all
// 16 keys -> every lane gets the global max, no second barrier). Key algebra:
// max key = max dist, tie -> max (NN-idx) = lowest idx = np.argmax. Center
// coords from LDS-staged cloud (96 KB, 1 block/CU anyway): broadcast ds_read.
// Exactness: wave max is bit-identical to one of that wave's dm values;
// distances >= 0 so float bits are order-preserving in the u64 key.
// ---------------------------------------------------------------------------
__global__ __attribute__((amdgpu_flat_work_group_size(1024, 1024),
                          amdgpu_waves_per_eu(4, 4)))
void k_fps(const float* __restrict__ xyz, float* __restrict__ out_kp) {
  __shared__ float sxyz[NN * 3];  // [idx][x,y,z]
  __shared__ int sIdx[SS];
  __shared__ u64 rkey[2][16];
  int b = blockIdx.x, t = threadIdx.x;
  const float* base = xyz + b * N3;
  v2f px[4], py[4], pz[4], dm[4];
#pragma unroll
  for (int j = 0; j < 4; ++j) {
    int n0 = j * 2048 + t, n1 = n0 + 1024;  // coalesced, disjoint cover [0,8192)
    px[j] = v2f{base[n0], base[n1]};
    py[j] = v2f{base[NN + n0], base[NN + n1]};
    pz[j] = v2f{base[2 * NN + n0], base[2 * NN + n1]};
    dm[j] = v2f{1e10f, 1e10f};
    sxyz[n0 * 3 + 0] = px[j].x;  // stage AoS copy for center re-loads
    sxyz[n0 * 3 + 1] = py[j].x;
    sxyz[n0 * 3 + 2] = pz[j].x;
    sxyz[n1 * 3 + 0] = px[j].y;
    sxyz[n1 * 3 + 1] = py[j].y;
    sxyz[n1 * 3 + 2] = pz[j].y;
  }
#pragma unroll
  for (int j = 0; j < 4; ++j) {
    // Opaque def: blocks rematerialization of the global loads.
    asm volatile("" : "+v"(px[j]), "+v"(py[j]), "+v"(pz[j]));
  }
  // staging writes become visible at iter-0's barrier, before first LDS read
  float cx = base[0], cy = base[NN], cz = base[2 * NN];
  int far = 0;
  int lane = t & 63, w = t >> 6;
  u32 tb = (u32)(NN - t);  // candidate base: cand = NN - gidx (1..8192; 0=none)
  for (int it = 0; it < SS; ++it) {
    if (t == 0) sIdx[it] = far;  // scan emits carry BEFORE update: idx[0]=0
    // negated center, broadcast to both halves (a + (-c) == a - c exactly)
    v2f ncx = v2f{-cx, -cx}, ncy = v2f{-cy, -cy}, ncz = v2f{-cz, -cz};
    float vmax = 0.0f;
#pragma unroll
    for (int j = 0; j < 4; ++j) {
      v2f dx = pk_add(px[j], ncx);
      v2f dy = pk_add(py[j], ncy);
      v2f dz = pk_add(pz[j], ncz);
      v2f xx = pk_mul(dx, dx);
      v2f yy = pk_mul(dy, dy);
      v2f s = pk_add(xx, yy);
      v2f zz = pk_mul(dz, dz);
      v2f d = pk_add(s, zz);  // ((dx^2+dy^2)+dz^2), numpy tree per half
      float a0 = fminf(dm[j].x, d.x);
      float a1 = fminf(dm[j].y, d.y);
      dm[j].x = a0;
      dm[j].y = a1;
      vmax = fmaxf(vmax, fmaxf(a0, a1));  // max3-foldable
    }
    // wave max (single chain, distances >= 0), then SALU broadcast
    vmax = dpp_maxf<0x111>(vmax);  // row_shr:1
    vmax = dpp_maxf<0x112>(vmax);  // row_shr:2
    vmax = dpp_maxf<0x114>(vmax);  // row_shr:4
    vmax = dpp_maxf<0x118>(vmax);  // row_shr:8
    vmax = dpp_maxf<0x142>(vmax);  // row_bcast:15
    vmax = dpp_maxf<0x143>(vmax);  // row_bcast:31 -> lane63 = wave max
    float wv = __int_as_float(__builtin_amdgcn_readlane(__float_as_int(vmax), 63));
    // find pass vs WAVE max: exact bit-equality (wv IS one of this wave's dm
    // values); descending gidx order so the LAST write = lowest gidx.
    u32 cand = 0;
#pragma unroll
    for (int j = 3; j >= 0; --j) {
      u32 v1 = tb - (u32)(j * 2048 + 1024);  // cand for .y half (higher gidx)
      u32 v0 = tb - (u32)(j * 2048);         // cand for .x half
      cand = (dm[j].y == wv) ? v1 : cand;
      cand = (dm[j].x == wv) ? v0 : cand;
    }
    cand = dpp_maxu<0x111>(cand);
    cand = dpp_maxu<0x112>(cand);
    cand = dpp_maxu<0x114>(cand);
    cand = dpp_maxu<0x118>(cand);
    cand = dpp_maxu<0x142>(cand);
    cand = dpp_maxu<0x143>(cand);  // lane63 = wave best (max cand = min gidx)
    int pb = it & 1;  // parity double-buffer: safe with one barrier/iter
    if (lane == 63) rkey[pb][w] = ((u64)__float_as_uint(wv) << 32) | cand;
    __syncthreads();  // the only barrier per iteration
    // block reduce over 16 wave keys: lane l loads key (l&15) — conflict-free
    // (16 distinct u64 addrs per 16-lane group, same-addr broadcast across
    // groups) — then xor-butterfly max within each 16-lane group.
    u64 kg = rkey[pb][lane & 15];
#pragma unroll
    for (int off = 1; off < 16; off <<= 1) {
      u64 o = __shfl_xor(kg, off, 64);
      kg = (o > kg) ? o : kg;
    }
    far = NN - (int)(u32)(kg & 0xffffffffu);
    // broadcast ds_read of the winner's coords (all lanes same address)
    cx = sxyz[far * 3 + 0];
    cy = sxyz[far * 3 + 1];
    cz = sxyz[far * 3 + 2];
  }
  __syncthreads();
  for (int i = t; i < SS; i += 1024) {
    int id = sIdx[i];
    out_kp[b * 1536 + i] = base[id];  // exact fp32 copies
    out_kp[b * 1536 + SS + i] = base[NN + id];
    out_kp[b * 1536 + 2 * SS + i] = base[2 * NN + id];
  }
}

// ---------------------------------------------------------------------------
// K2: per (b,s) row, sorted top-24 nearest (dist asc, idx asc) — prefixes give
// K=8/16/24 and base K=16 (lax.top_k stable tie-break). One wave per row.
// KD=14 per-lane depth (r11 win: non-fps time 634 -> 466 us): top-24 indices
// are ~uniform mod 64, P(any lane holds >=15 of 24) < 1e-15 over all rows.
// d = (|a|^2+|q|^2) - 2*dot, all rn ops, matching the numpy expression tree.
// ---------------------------------------------------------------------------
__global__ __launch_bounds__(256) void k_knn(const float* __restrict__ xyz,
                                             const float* __restrict__ kp,
                                             u16* __restrict__ knn) {
  int t = threadIdx.x;
  int row = blockIdx.x * 4 + (t >> 6);
  int lane = t & 63;
  int b = row >> 9, s = row & (SS - 1);
  const float* base = xyz + b * N3;
  float ax = kp[b * 1536 + s];
  float ay = kp[b * 1536 + SS + s];
  float az = kp[b * 1536 + 2 * SS + s];
  float aw = __fadd_rn(__fadd_rn(__fmul_rn(ax, ax), __fmul_rn(ay, ay)), __fmul_rn(az, az));
  u64 arr[KD];
#pragma unroll
  for (int i = 0; i < KD; ++i) arr[i] = ~0ull;
  for (int c = 0; c < 128; ++c) {
    int n = c * 64 + lane;
    float qx = base[n], qy = base[NN + n], qz = base[2 * NN + n];
    float qw = __fadd_rn(__fadd_rn(__fmul_rn(qx, qx), __fmul_rn(qy, qy)), __fmul_rn(qz, qz));
    float dot = __fadd_rn(__fadd_rn(__fmul_rn(ax, qx), __fmul_rn(ay, qy)), __fmul_rn(az, qz));
    float d = __fsub_rn(__fadd_rn(aw, qw), __fmul_rn(2.0f, dot));
    u32 ub = __float_as_uint(d);
    ub ^= (ub & 0x80000000u) ? 0xFFFFFFFFu : 0x80000000u;  // order-preserving map
    u64 key = ((u64)ub << 32) | (u32)n;
    if (key < arr[KD - 1]) {  // branchless descending insertion (arr asc)
#pragma unroll
      for (int i = KD - 1; i >= 1; --i) {
        u64 am = arr[i - 1];
        arr[i] = (am > key) ? am : ((arr[i] > key) ? key : arr[i]);
      }
      if (arr[0] > key) arr[0] = key;
    }
  }
  // merge 64 sorted lists: 24 x (wave-min of heads, winner pops). keys unique.
  u64 mine = 0;
  for (int it = 0; it < 24; ++it) {
    u64 m = arr[0];
#pragma unroll
    for (int off = 1; off < 64; off <<= 1) {
      u64 o = __shfl_xor(m, off, 64);
      m = (o < m) ? o : m;
    }
    if (lane == it) mine = m;
    if (arr[0] == m) {
#pragma unroll
      for (int i = 0; i < KD - 1; ++i) arr[i] = arr[i + 1];
      arr[KD - 1] = ~0ull;
    }
  }
  if (lane < 24) knn[row * 24 + lane] = (u16)(mine & 0xFFFFu);
}

// ---------------------------------------------------------------------------
// K3: base SA MLP. feat[16][6] = [rel_xyz | pts]; 6->64 relu -> 64->128; max
// over K=16. Wave = one row; each thread owns 2 output channels (lane,
// lane+64) with W2 rows in registers; h1 read as explicit float4 broadcast.
// Block = 4 rows in flight x 2 groups = 8 rows.
// ---------------------------------------------------------------------------
__global__ __launch_bounds__(256) void k_base(
    const float* __restrict__ xyz, const float* __restrict__ pts,
    const float* __restrict__ kp, const u16* __restrict__ knn,
    const float* __restrict__ W1, const float* __restrict__ b1,
    const float* __restrict__ W2, const float* __restrict__ b2,
    float* __restrict__ out) {
  __shared__ float sW1T[6 * 64];     // [c][o]
  __shared__ float sb1[64];
  __shared__ float sfeat[4][16 * 6]; // [row][k*6+c]
  __shared__ float sh1[4][16 * 64];  // [row][k*64+o]
  int t = threadIdx.x, lane = t & 63, w = t >> 6;
  int b = blockIdx.x >> 6, s0 = (blockIdx.x & 63) * 8;
  for (int i = t; i < 384; i += 256) {
    int o = i / 6, c = i - o * 6;
    sW1T[c * 64 + o] = W1[i];
  }
  if (t < 64) sb1[t] = b1[t];
  float wgtA[64], wgtB[64];
#pragma unroll
  for (int j = 0; j < 64; ++j) {
    wgtA[j] = W2[lane * 64 + j];
    wgtB[j] = W2[(lane + 64) * 64 + j];
  }
  float b2A = b2[lane], b2B = b2[lane + 64];
  __syncthreads();
  for (int g = 0; g < 2; ++g) {
    for (int i = t; i < 384; i += 256) {  // 4 rows x 16 k x 6 c
      int rr = i / 96, rem = i - rr * 96, k = rem / 6, c = rem - k * 6;
      int s = s0 + g * 4 + rr, row = b * SS + s;
      int id = knn[row * 24 + k];  // first 16 of sorted top-24 = base KNN
      float val;
      if (c < 3) {
        val = __fsub_rn(xyz[b * N3 + c * NN + id], kp[b * 1536 + c * SS + s]);
      } else {
        val = pts[b * N3 + (c - 3) * NN + id];
      }
      sfeat[rr][k * 6 + c] = val;
    }
    __syncthreads();
#pragma unroll
    for (int m = 0; m < 16; ++m) {  // 4 rows x 1024 h1 entries / 256 thr
      int u = m * 256 + t;
      int rr = u >> 10, rem = u & 1023, k = rem >> 6, o = rem & 63;
      float acc = sb1[o];
#pragma unroll
      for (int c = 0; c < 6; ++c) acc = fmaf(sfeat[rr][k * 6 + c], sW1T[c * 64 + o], acc);
      sh1[rr][k * 64 + o] = fmaxf(acc, 0.f);
    }
    __syncthreads();
    float bestA = -1e30f, bestB = -1e30f;
#pragma unroll
    for (int k = 0; k < 16; ++k) {
      const float4* h4 = (const float4*)&sh1[w][k * 64];  // wave-uniform bcast
      float a0 = 0.f, a1 = 0.f;
#pragma unroll
      for (int j = 0; j < 16; ++j) {
        float4 hv = h4[j];
        a0 = fmaf(hv.x, wgtA[4 * j], a0);
        a0 = fmaf(hv.y, wgtA[4 * j + 1], a0);
        a0 = fmaf(hv.z, wgtA[4 * j + 2], a0);
        a0 = fmaf(hv.w, wgtA[4 * j + 3], a0);
        a1 = fmaf(hv.x, wgtB[4 * j], a1);
        a1 = fmaf(hv.y, wgtB[4 * j + 1], a1);
        a1 = fmaf(hv.z, wgtB[4 * j + 2], a1);
        a1 = fmaf(hv.w, wgtB[4 * j + 3], a1);
      }
      bestA = fmaxf(bestA, a0);
      bestB = fmaxf(bestB, a1);
    }
    int s = s0 + g * 4 + w;
    out[24576 + b * 262144 + lane * 512 + s] = bestA + b2A;
    out[24576 + b * 262144 + (lane + 64) * 512 + s] = bestB + b2B;
    __syncthreads();  // protect sfeat/sh1 before next group overwrites
  }
}

// ---------------------------------------------------------------------------
// K4: multi-scale MLPs, scale = blockIdx.y, K = 8*(scale+1), rel-xyz only.
// Same 2-channels-per-thread structure. Output channels 128*(scale+1)..+128.
// ---------------------------------------------------------------------------
__global__ __launch_bounds__(256) void k_ms(
    const float* __restrict__ xyz, const float* __restrict__ kp,
    const u16* __restrict__ knn, const float* __restrict__ msW1,
    const float* __restrict__ msb1, const float* __restrict__ msW2,
    const float* __restrict__ msb2, float* __restrict__ out) {
  int scale = blockIdx.y;
  int kk = 8 * (scale + 1);
  __shared__ float sW1T[3 * 64];
  __shared__ float sb1[64];
  __shared__ float sfeat[4][24 * 3];
  __shared__ float sh1[4][24 * 64];
  int t = threadIdx.x, lane = t & 63, w = t >> 6;
  int b = blockIdx.x >> 6, s0 = (blockIdx.x & 63) * 8;
  const float* W1s = msW1 + scale * 192;
  for (int i = t; i < 192; i += 256) {
    int o = i / 3, c = i - o * 3;
    sW1T[c * 64 + o] = W1s[i];
  }
  if (t < 64) sb1[t] = msb1[scale * 64 + t];
  float wgtA[64], wgtB[64];
#pragma unroll
  for (int j = 0; j < 64; ++j) {
    wgtA[j] = msW2[scale * 8192 + lane * 64 + j];
    wgtB[j] = msW2[scale * 8192 + (lane + 64) * 64 + j];
  }
  float b2A = msb2[scale * 128 + lane], b2B = msb2[scale * 128 + lane + 64];
  __syncthreads();
  int co = 128 * (scale + 1);
  for (int g = 0; g < 2; ++g) {
    int nfeat = 4 * kk * 3;
    for (int i = t; i < nfeat; i += 256) {  // 4 rows x kk k x 3 c
      int kk3 = kk * 3;
      int rr = i / kk3, rem = i - rr * kk3, k = rem / 3, c = rem - k * 3;
      int s = s0 + g * 4 + rr, row = b * SS + s;
      int id = knn[row * 24 + k];
      sfeat[rr][k * 3 + c] = __fsub_rn(xyz[b * N3 + c * NN + id], kp[b * 1536 + c * SS + s]);
    }
    __syncthreads();
    for (int rr = 0; rr < 4; ++rr) {  // h1 for kk*64 entries per row
      for (int u = t; u < kk * 64; u += 256) {
        int k = u >> 6, o = u & 63;
        float acc = sb1[o];
        acc = fmaf(sfeat[rr][k * 3 + 0], sW1T[o], acc);
        acc = fmaf(sfeat[rr][k * 3 + 1], sW1T[64 + o], acc);
        acc = fmaf(sfeat[rr][k * 3 + 2], sW1T[128 + o], acc);
        sh1[rr][k * 64 + o] = fmaxf(acc, 0.f);
      }
    }
    __syncthreads();
    float bestA = -1e30f, bestB = -1e30f;
    for (int k = 0; k < kk; ++k) {  // kk uniform across block -> no divergence
      const float4* h4 = (const float4*)&sh1[w][k * 64];
      float a0 = 0.f, a1 = 0.f;
#pragma unroll
      for (int j = 0; j < 16; ++j) {
        float4 hv = h4[j];
        a0 = fmaf(hv.x, wgtA[4 * j], a0);
        a0 = fmaf(hv.y, wgtA[4 * j + 1], a0);
        a0 = fmaf(hv.z, wgtA[4 * j + 2], a0);
        a0 = fmaf(hv.w, wgtA[4 * j + 3], a0);
        a1 = fmaf(hv.x, wgtB[4 * j], a1);
        a1 = fmaf(hv.y, wgtB[4 * j + 1], a1);
        a1 = fmaf(hv.z, wgtB[4 * j + 2], a1);
        a1 = fmaf(hv.w, wgtB[4 * j + 3], a1);
      }
      bestA = fmaxf(bestA, a0);
      bestB = fmaxf(bestB, a1);
    }
    int s = s0 + g * 4 + w;
    out[24576 + b * 262144 + (co + lane) * 512 + s] = bestA + b2A;
    out[24576 + b * 262144 + (co + lane + 64) * 512 + s] = bestB + b2B;
    __syncthreads();
  }
}

// ---------------------------------------------------------------------------
extern "C" void kernel_launch(void* const* d_in, const int* in_sizes, int n_in,
                              void* d_out, int out_size, void* d_ws, size_t ws_size,
                              hipStream_t stream) {
  const float* xyz = (const float*)d_in[0];    // l0_xyz  [B,3,N] f32
  const float* pts = (const float*)d_in[1];    // l0_points
  const float* sa_W1 = (const float*)d_in[2];  // [64,6]
  const float* sa_b1 = (const float*)d_in[3];  // [64]
  const float* sa_W2 = (const float*)d_in[4];  // [128,64]
  const float* sa_b2 = (const float*)d_in[5];  // [128]
  const float* ms_W1 = (const float*)d_in[6];  // [3,64,3]
  const float* ms_b1 = (const float*)d_in[7];  // [3,64]
  const float* ms_W2 = (const float*)d_in[8];  // [3,128,64]
  const float* ms_b2 = (const float*)d_in[9];  // [3,128]
  float* out = (float*)d_out;
  const float* kp = (const float*)d_out;  // keypoints written by k_fps

  // workspace: knn u16[B*S*24] = 384 KB
  u16* knn = (u16*)d_ws;

  k_fps<<<BB, 1024, 0, stream>>>(xyz, out);
  k_knn<<<(BB * SS) / 4, 256, 0, stream>>>(xyz, kp, knn);
  k_base<<<BB * 64, 256, 0, stream>>>(xyz, pts, kp, knn, sa_W1, sa_b1, sa_W2, sa_b2, out);
  k_ms<<<dim3(BB * 64, 3), 256, 0, stream>>>(xyz, kp, knn, ms_W1, ms_b1, ms_W2, ms_b2, out);
}

// Round 2
// 1145.768 us; speedup vs baseline: 1.0070x; 1.0070x over previous
//
#include <hip/hip_runtime.h>

#define BB 16
#define NN 8192
#define SS 512
#define N3 (3 * NN)  // 24576 elements per batch per tensor
#define KD 14        // per-lane KNN list depth (see k_knn comment)

typedef unsigned short u16;
typedef unsigned int u32;
typedef unsigned long long u64;
typedef float v2f __attribute__((ext_vector_type(2)));

// Packed fp32 ops (VOP3P, 2 points/inst). Per-half rounding is IEEE rn —
// bit-identical to scalar __fadd_rn/__fmul_rn.
__device__ __forceinline__ v2f pk_add(v2f a, v2f b) {
  v2f r;
  asm("v_pk_add_f32 %0, %1, %2" : "=v"(r) : "v"(a), "v"(b));
  return r;
}
__device__ __forceinline__ v2f pk_mul(v2f a, v2f b) {
  v2f r;
  asm("v_pk_mul_f32 %0, %1, %2" : "=v"(r) : "v"(a), "v"(b));
  return r;
}

// ---------------------------------------------------------------------------
// K1: farthest point sampling, fp32, bit-exact vs numpy. r15.
// History: r13 = 256 thr (1 wave/SIMD) 544us, latency-bound (VALUBusy 57% of
// active-CU cap; DPP-chain + readlane + LDS-broadcast + barrier stalls
// unhidden). r14 = 1024 thr (4 waves/SIMD) 661us, WORSE: per-wave fixed
// overhead (2 DPP chains + readlane + find + reduce ~80 insts) paid 4x
// outweighed the hiding. r15 interpolates to 512 thr = 2 waves/SIMD AND cuts
// the per-wave serial chain: thread-local find vs the thread's OWN vmax
// (no cross-lane dep, no readlane round-trip), pack ONE u64 key
// (dist_bits<<32 | NN-idx), single 6-step shfl_xor u64-max butterfly
// (replaces both DPP chains + readlane + wave-find). Exactness: vmax is
// bit-identical to one of this thread's dm values; d >= +0 so float bits are
// order-preserving as u32; max key = max dist, tie -> max (NN-idx) = lowest
// idx = np.argmax. Within-thread ties: descending-j find, last write wins =
// lowest idx. lane0 writes the wave key to rkey[parity][w] -> ONE barrier ->
// 8-key block reduce: lane loads rkey[lane&7] (conflict-free, 8-way broadcast
// groups) + 3-step shfl_xor u64 butterfly -> every lane has the global key.
// Center coords via broadcast ds_read from the LDS-staged cloud (96 KB).
// ---------------------------------------------------------------------------
__global__ __attribute__((amdgpu_flat_work_group_size(512, 512),
                          amdgpu_waves_per_eu(2, 2)))
void k_fps(const float* __restrict__ xyz, float* __restrict__ out_kp) {
  __shared__ float sxyz[NN * 3];  // [idx][x,y,z]
  __shared__ int sIdx[SS];
  __shared__ u64 rkey[2][8];
  int b = blockIdx.x, t = threadIdx.x;
  const float* base = xyz + b * N3;
  v2f px[8], py[8], pz[8], dm[8];
#pragma unroll
  for (int j = 0; j < 8; ++j) {
    int n0 = j * 1024 + t, n1 = n0 + 512;  // coalesced, disjoint cover [0,8192)
    px[j] = v2f{base[n0], base[n1]};
    py[j] = v2f{base[NN + n0], base[NN + n1]};
    pz[j] = v2f{base[2 * NN + n0], base[2 * NN + n1]};
    dm[j] = v2f{1e10f, 1e10f};
    sxyz[n0 * 3 + 0] = px[j].x;  // stage AoS copy for center re-loads
    sxyz[n0 * 3 + 1] = py[j].x;
    sxyz[n0 * 3 + 2] = pz[j].x;
    sxyz[n1 * 3 + 0] = px[j].y;
    sxyz[n1 * 3 + 1] = py[j].y;
    sxyz[n1 * 3 + 2] = pz[j].y;
  }
#pragma unroll
  for (int j = 0; j < 8; ++j) {
    // Opaque def: blocks rematerialization of the global loads.
    asm volatile("" : "+v"(px[j]), "+v"(py[j]), "+v"(pz[j]));
  }
  // staging writes become visible at iter-0's barrier, before first LDS read
  float cx = base[0], cy = base[NN], cz = base[2 * NN];
  int far = 0;
  int lane = t & 63, w = t >> 6;
  u32 tb = (u32)(NN - t);  // candidate base: cand = NN - gidx (1..8192; 0=none)
  for (int it = 0; it < SS; ++it) {
    if (t == 0) sIdx[it] = far;  // scan emits carry BEFORE update: idx[0]=0
    // negated center, broadcast to both halves (a + (-c) == a - c exactly)
    v2f ncx = v2f{-cx, -cx}, ncy = v2f{-cy, -cy}, ncz = v2f{-cz, -cz};
    float vmax = 0.0f;
#pragma unroll
    for (int j = 0; j < 8; ++j) {
      v2f dx = pk_add(px[j], ncx);
      v2f dy = pk_add(py[j], ncy);
      v2f dz = pk_add(pz[j], ncz);
      v2f xx = pk_mul(dx, dx);
      v2f yy = pk_mul(dy, dy);
      v2f s = pk_add(xx, yy);
      v2f zz = pk_mul(dz, dz);
      v2f d = pk_add(s, zz);  // ((dx^2+dy^2)+dz^2), numpy tree per half
      float a0 = fminf(dm[j].x, d.x);
      float a1 = fminf(dm[j].y, d.y);
      dm[j].x = a0;
      dm[j].y = a1;
      vmax = fmaxf(vmax, fmaxf(a0, a1));  // max3-foldable
    }
    // thread-local find vs this thread's OWN max: exact bit-equality (vmax IS
    // one of this thread's dm values). Descending gidx order -> LAST write =
    // lowest gidx within the thread.
    u32 cand = 0;
#pragma unroll
    for (int j = 7; j >= 0; --j) {
      u32 v1 = tb - (u32)(j * 1024 + 512);  // cand for .y half (higher gidx)
      u32 v0 = tb - (u32)(j * 1024);        // cand for .x half
      cand = (dm[j].y == vmax) ? v1 : cand;
      cand = (dm[j].x == vmax) ? v0 : cand;
    }
    // one packed key per thread; 6-step u64 max butterfly -> all lanes hold
    // the wave best (max dist, tie -> max cand = min gidx). No readlane, no
    // separate value/cand chains.
    u64 key = ((u64)__float_as_uint(vmax) << 32) | cand;
#pragma unroll
    for (int off = 1; off < 64; off <<= 1) {
      u64 o = __shfl_xor(key, off, 64);
      key = (o > key) ? o : key;
    }
    int pb = it & 1;  // parity double-buffer: safe with one barrier/iter
    if (lane == 0) rkey[pb][w] = key;
    __syncthreads();  // the only barrier per iteration
    // block reduce over 8 wave keys: lane l loads key (l&7) — conflict-free
    // (8 distinct u64 addrs per 8-lane group, same-addr broadcast across
    // groups) — then 3-step xor-butterfly max within each 8-lane group.
    u64 kg = rkey[pb][lane & 7];
#pragma unroll
    for (int off = 1; off < 8; off <<= 1) {
      u64 o = __shfl_xor(kg, off, 64);
      kg = (o > kg) ? o : kg;
    }
    far = NN - (int)(u32)(kg & 0xffffffffu);
    // broadcast ds_read of the winner's coords (all lanes same address)
    cx = sxyz[far * 3 + 0];
    cy = sxyz[far * 3 + 1];
    cz = sxyz[far * 3 + 2];
  }
  __syncthreads();
  for (int i = t; i < SS; i += 512) {
    int id = sIdx[i];
    out_kp[b * 1536 + i] = base[id];  // exact fp32 copies
    out_kp[b * 1536 + SS + i] = base[NN + id];
    out_kp[b * 1536 + 2 * SS + i] = base[2 * NN + id];
  }
}

// ---------------------------------------------------------------------------
// K2: per (b,s) row, sorted top-24 nearest (dist asc, idx asc) — prefixes give
// K=8/16/24 and base K=16 (lax.top_k stable tie-break). One wave per row.
// KD=14 per-lane depth (r11 win: non-fps time 634 -> 466 us): top-24 indices
// are ~uniform mod 64, P(any lane holds >=15 of 24) < 1e-15 over all rows.
// d = (|a|^2+|q|^2) - 2*dot, all rn ops, matching the numpy expression tree.
// ---------------------------------------------------------------------------
__global__ __launch_bounds__(256) void k_knn(const float* __restrict__ xyz,
                                             const float* __restrict__ kp,
                                             u16* __restrict__ knn) {
  int t = threadIdx.x;
  int row = blockIdx.x * 4 + (t >> 6);
  int lane = t & 63;
  int b = row >> 9, s = row & (SS - 1);
  const float* base = xyz + b * N3;
  float ax = kp[b * 1536 + s];
  float ay = kp[b * 1536 + SS + s];
  float az = kp[b * 1536 + 2 * SS + s];
  float aw = __fadd_rn(__fadd_rn(__fmul_rn(ax, ax), __fmul_rn(ay, ay)), __fmul_rn(az, az));
  u64 arr[KD];
#pragma unroll
  for (int i = 0; i < KD; ++i) arr[i] = ~0ull;
  for (int c = 0; c < 128; ++c) {
    int n = c * 64 + lane;
    float qx = base[n], qy = base[NN + n], qz = base[2 * NN + n];
    float qw = __fadd_rn(__fadd_rn(__fmul_rn(qx, qx), __fmul_rn(qy, qy)), __fmul_rn(qz, qz));
    float dot = __fadd_rn(__fadd_rn(__fmul_rn(ax, qx), __fmul_rn(ay, qy)), __fmul_rn(az, qz));
    float d = __fsub_rn(__fadd_rn(aw, qw), __fmul_rn(2.0f, dot));
    u32 ub = __float_as_uint(d);
    ub ^= (ub & 0x80000000u) ? 0xFFFFFFFFu : 0x80000000u;  // order-preserving map
    u64 key = ((u64)ub << 32) | (u32)n;
    if (key < arr[KD - 1]) {  // branchless descending insertion (arr asc)
#pragma unroll
      for (int i = KD - 1; i >= 1; --i) {
        u64 am = arr[i - 1];
        arr[i] = (am > key) ? am : ((arr[i] > key) ? key : arr[i]);
      }
      if (arr[0] > key) arr[0] = key;
    }
  }
  // merge 64 sorted lists: 24 x (wave-min of heads, winner pops). keys unique.
  u64 mine = 0;
  for (int it = 0; it < 24; ++it) {
    u64 m = arr[0];
#pragma unroll
    for (int off = 1; off < 64; off <<= 1) {
      u64 o = __shfl_xor(m, off, 64);
      m = (o < m) ? o : m;
    }
    if (lane == it) mine = m;
    if (arr[0] == m) {
#pragma unroll
      for (int i = 0; i < KD - 1; ++i) arr[i] = arr[i + 1];
      arr[KD - 1] = ~0ull;
    }
  }
  if (lane < 24) knn[row * 24 + lane] = (u16)(mine & 0xFFFFu);
}

// ---------------------------------------------------------------------------
// K3: base SA MLP. feat[16][6] = [rel_xyz | pts]; 6->64 relu -> 64->128; max
// over K=16. Wave = one row; each thread owns 2 output channels (lane,
// lane+64) with W2 rows in registers; h1 read as explicit float4 broadcast.
// Block = 4 rows in flight x 2 groups = 8 rows.
// ---------------------------------------------------------------------------
__global__ __launch_bounds__(256) void k_base(
    const float* __restrict__ xyz, const float* __restrict__ pts,
    const float* __restrict__ kp, const u16* __restrict__ knn,
    const float* __restrict__ W1, const float* __restrict__ b1,
    const float* __restrict__ W2, const float* __restrict__ b2,
    float* __restrict__ out) {
  __shared__ float sW1T[6 * 64];     // [c][o]
  __shared__ float sb1[64];
  __shared__ float sfeat[4][16 * 6]; // [row][k*6+c]
  __shared__ float sh1[4][16 * 64];  // [row][k*64+o]
  int t = threadIdx.x, lane = t & 63, w = t >> 6;
  int b = blockIdx.x >> 6, s0 = (blockIdx.x & 63) * 8;
  for (int i = t; i < 384; i += 256) {
    int o = i / 6, c = i - o * 6;
    sW1T[c * 64 + o] = W1[i];
  }
  if (t < 64) sb1[t] = b1[t];
  float wgtA[64], wgtB[64];
#pragma unroll
  for (int j = 0; j < 64; ++j) {
    wgtA[j] = W2[lane * 64 + j];
    wgtB[j] = W2[(lane + 64) * 64 + j];
  }
  float b2A = b2[lane], b2B = b2[lane + 64];
  __syncthreads();
  for (int g = 0; g < 2; ++g) {
    for (int i = t; i < 384; i += 256) {  // 4 rows x 16 k x 6 c
      int rr = i / 96, rem = i - rr * 96, k = rem / 6, c = rem - k * 6;
      int s = s0 + g * 4 + rr, row = b * SS + s;
      int id = knn[row * 24 + k];  // first 16 of sorted top-24 = base KNN
      float val;
      if (c < 3) {
        val = __fsub_rn(xyz[b * N3 + c * NN + id], kp[b * 1536 + c * SS + s]);
      } else {
        val = pts[b * N3 + (c - 3) * NN + id];
      }
      sfeat[rr][k * 6 + c] = val;
    }
    __syncthreads();
#pragma unroll
    for (int m = 0; m < 16; ++m) {  // 4 rows x 1024 h1 entries / 256 thr
      int u = m * 256 + t;
      int rr = u >> 10, rem = u & 1023, k = rem >> 6, o = rem & 63;
      float acc = sb1[o];
#pragma unroll
      for (int c = 0; c < 6; ++c) acc = fmaf(sfeat[rr][k * 6 + c], sW1T[c * 64 + o], acc);
      sh1[rr][k * 64 + o] = fmaxf(acc, 0.f);
    }
    __syncthreads();
    float bestA = -1e30f, bestB = -1e30f;
#pragma unroll
    for (int k = 0; k < 16; ++k) {
      const float4* h4 = (const float4*)&sh1[w][k * 64];  // wave-uniform bcast
      float a0 = 0.f, a1 = 0.f;
#pragma unroll
      for (int j = 0; j < 16; ++j) {
        float4 hv = h4[j];
        a0 = fmaf(hv.x, wgtA[4 * j], a0);
        a0 = fmaf(hv.y, wgtA[4 * j + 1], a0);
        a0 = fmaf(hv.z, wgtA[4 * j + 2], a0);
        a0 = fmaf(hv.w, wgtA[4 * j + 3], a0);
        a1 = fmaf(hv.x, wgtB[4 * j], a1);
        a1 = fmaf(hv.y, wgtB[4 * j + 1], a1);
        a1 = fmaf(hv.z, wgtB[4 * j + 2], a1);
        a1 = fmaf(hv.w, wgtB[4 * j + 3], a1);
      }
      bestA = fmaxf(bestA, a0);
      bestB = fmaxf(bestB, a1);
    }
    int s = s0 + g * 4 + w;
    out[24576 + b * 262144 + lane * 512 + s] = bestA + b2A;
    out[24576 + b * 262144 + (lane + 64) * 512 + s] = bestB + b2B;
    __syncthreads();  // protect sfeat/sh1 before next group overwrites
  }
}

// ---------------------------------------------------------------------------
// K4: multi-scale MLPs, scale = blockIdx.y, K = 8*(scale+1), rel-xyz only.
// Same 2-channels-per-thread structure. Output channels 128*(scale+1)..+128.
// ---------------------------------------------------------------------------
__global__ __launch_bounds__(256) void k_ms(
    const float* __restrict__ xyz, const float* __restrict__ kp,
    const u16* __restrict__ knn, const float* __restrict__ msW1,
    const float* __restrict__ msb1, const float* __restrict__ msW2,
    const float* __restrict__ msb2, float* __restrict__ out) {
  int scale = blockIdx.y;
  int kk = 8 * (scale + 1);
  __shared__ float sW1T[3 * 64];
  __shared__ float sb1[64];
  __shared__ float sfeat[4][24 * 3];
  __shared__ float sh1[4][24 * 64];
  int t = threadIdx.x, lane = t & 63, w = t >> 6;
  int b = blockIdx.x >> 6, s0 = (blockIdx.x & 63) * 8;
  const float* W1s = msW1 + scale * 192;
  for (int i = t; i < 192; i += 256) {
    int o = i / 3, c = i - o * 3;
    sW1T[c * 64 + o] = W1s[i];
  }
  if (t < 64) sb1[t] = msb1[scale * 64 + t];
  float wgtA[64], wgtB[64];
#pragma unroll
  for (int j = 0; j < 64; ++j) {
    wgtA[j] = msW2[scale * 8192 + lane * 64 + j];
    wgtB[j] = msW2[scale * 8192 + (lane + 64) * 64 + j];
  }
  float b2A = msb2[scale * 128 + lane], b2B = msb2[scale * 128 + lane + 64];
  __syncthreads();
  int co = 128 * (scale + 1);
  for (int g = 0; g < 2; ++g) {
    int nfeat = 4 * kk * 3;
    for (int i = t; i < nfeat; i += 256) {  // 4 rows x kk k x 3 c
      int kk3 = kk * 3;
      int rr = i / kk3, rem = i - rr * kk3, k = rem / 3, c = rem - k * 3;
      int s = s0 + g * 4 + rr, row = b * SS + s;
      int id = knn[row * 24 + k];
      sfeat[rr][k * 3 + c] = __fsub_rn(xyz[b * N3 + c * NN + id], kp[b * 1536 + c * SS + s]);
    }
    __syncthreads();
    for (int rr = 0; rr < 4; ++rr) {  // h1 for kk*64 entries per row
      for (int u = t; u < kk * 64; u += 256) {
        int k = u >> 6, o = u & 63;
        float acc = sb1[o];
        acc = fmaf(sfeat[rr][k * 3 + 0], sW1T[o], acc);
        acc = fmaf(sfeat[rr][k * 3 + 1], sW1T[64 + o], acc);
        acc = fmaf(sfeat[rr][k * 3 + 2], sW1T[128 + o], acc);
        sh1[rr][k * 64 + o] = fmaxf(acc, 0.f);
      }
    }
    __syncthreads();
    float bestA = -1e30f, bestB = -1e30f;
    for (int k = 0; k < kk; ++k) {  // kk uniform across block -> no divergence
      const float4* h4 = (const float4*)&sh1[w][k * 64];
      float a0 = 0.f, a1 = 0.f;
#pragma unroll
      for (int j = 0; j < 16; ++j) {
        float4 hv = h4[j];
        a0 = fmaf(hv.x, wgtA[4 * j], a0);
        a0 = fmaf(hv.y, wgtA[4 * j + 1], a0);
        a0 = fmaf(hv.z, wgtA[4 * j + 2], a0);
        a0 = fmaf(hv.w, wgtA[4 * j + 3], a0);
        a1 = fmaf(hv.x, wgtB[4 * j], a1);
        a1 = fmaf(hv.y, wgtB[4 * j + 1], a1);
        a1 = fmaf(hv.z, wgtB[4 * j + 2], a1);
        a1 = fmaf(hv.w, wgtB[4 * j + 3], a1);
      }
      bestA = fmaxf(bestA, a0);
      bestB = fmaxf(bestB, a1);
    }
    int s = s0 + g * 4 + w;
    out[24576 + b * 262144 + (co + lane) * 512 + s] = bestA + b2A;
    out[24576 + b * 262144 + (co + lane + 64) * 512 + s] = bestB + b2B;
    __syncthreads();
  }
}

// ---------------------------------------------------------------------------
extern "C" void kernel_launch(void* const* d_in, const int* in_sizes, int n_in,
                              void* d_out, int out_size, void* d_ws, size_t ws_size,
                              hipStream_t stream) {
  const float* xyz = (const float*)d_in[0];    // l0_xyz  [B,3,N] f32
  const float* pts = (const float*)d_in[1];    // l0_points
  const float* sa_W1 = (const float*)d_in[2];  // [64,6]
  const float* sa_b1 = (const float*)d_in[3];  // [64]
  const float* sa_W2 = (const float*)d_in[4];  // [128,64]
  const float* sa_b2 = (const float*)d_in[5];  // [128]
  const float* ms_W1 = (const float*)d_in[6];  // [3,64,3]
  const float* ms_b1 = (const float*)d_in[7];  // [3,64]
  const float* ms_W2 = (const float*)d_in[8];  // [3,128,64]
  const float* ms_b2 = (const float*)d_in[9];  // [3,128]
  float* out = (float*)d_out;
  const float* kp = (const float*)d_out;  // keypoints written by k_fps

  // workspace: knn u16[B*S*24] = 384 KB
  u16* knn = (u16*)d_ws;

  k_fps<<<BB, 512, 0, stream>>>(xyz, out);
  k_knn<<<(BB * SS) / 4, 256, 0, stream>>>(xyz, kp, knn);
  k_base<<<BB * 64, 256, 0, stream>>>(xyz, pts, kp, knn, sa_W1, sa_b1, sa_W2, sa_b2, out);
  k_ms<<<dim3(BB * 64, 3), 256, 0, stream>>>(xyz, kp, knn, ms_W1, ms_b1, ms_W2, ms_b2, out);
}

// Round 3
// 1004.854 us; speedup vs baseline: 1.1483x; 1.1402x over previous
//
#include <hip/hip_runtime.h>

#define BB 16
#define NN 8192
#define SS 512
#define N3 (3 * NN)  // 24576 elements per batch per tensor
#define KD 14        // per-lane KNN list depth (see k_knn comment)

typedef unsigned short u16;
typedef unsigned int u32;
typedef unsigned long long u64;
typedef float v2f __attribute__((ext_vector_type(2)));

// Packed fp32 ops (VOP3P, 2 points/inst). Per-half rounding is IEEE rn —
// bit-identical to scalar __fadd_rn/__fmul_rn.
__device__ __forceinline__ v2f pk_add(v2f a, v2f b) {
  v2f r;
  asm("v_pk_add_f32 %0, %1, %2" : "=v"(r) : "v"(a), "v"(b));
  return r;
}
__device__ __forceinline__ v2f pk_mul(v2f a, v2f b) {
  v2f r;
  asm("v_pk_mul_f32 %0, %1, %2" : "=v"(r) : "v"(a), "v"(b));
  return r;
}

// u64 max step over a DPP lane-shift: shift both 32-bit halves with the same
// control (old=0 is the identity for max of our non-negative keys), then one
// v_cmp_lt_u64 + 2 cndmask. Stays entirely on the VALU pipe — r15's lesson:
// __shfl_xor is ds_bpermute (LDS pipe, ~40+cy dependent) and 9 such steps on
// the serial path cost ~+500cy/iter (544 -> 658 us).
template <int CTRL>
__device__ __forceinline__ u64 dpp_maxk(u64 k) {
  u32 lo = (u32)k, hi = (u32)(k >> 32);
  u32 slo = (u32)__builtin_amdgcn_update_dpp(0, (int)lo, CTRL, 0xf, 0xf, false);
  u32 shi = (u32)__builtin_amdgcn_update_dpp(0, (int)hi, CTRL, 0xf, 0xf, false);
  u64 s = ((u64)shi << 32) | (u64)slo;
  return (s > k) ? s : k;
}
__device__ __forceinline__ u64 maxk(u64 a, u64 b) { return (a > b) ? a : b; }

// ---------------------------------------------------------------------------
// K1: farthest point sampling, fp32, bit-exact vs numpy. r16.
// History: r13 = 256 thr (1 wave/SIMD, DPP value chain + readlane + find +
// DPP cand chain) 544us, latency-bound. r14 = 1024 thr, 661us (4x per-wave
// overhead). r15 = 512 thr + u64 __shfl_xor butterflies, 658us: shfl =
// ds_bpermute = LDS-pipe latency (~+500cy/iter serial) — NOT hidden at 2
// waves/SIMD. r16 = 512 thr, all cross-lane on the VALU pipe:
//   dist loop (8 v2f/thread) -> thread-local find vs OWN vmax (no cross-lane
//   dep, no readlane) -> ONE u64 DPP max chain (shr1,2,4,8,bcast15,bcast31;
//   5 insts/step, VALU latency) -> lane63 ds_write key -> ONE barrier ->
//   every thread broadcast-reads all 8 wave keys (one pipelined LDS round
//   trip) + redundant 7-compare VALU tree (no cross-lane at all) -> far ->
//   broadcast ds_read of winner coords.
// Exactness: vmax is bit-identical to one of this thread's dm values; d >= +0
// so float bits are order-preserving as u32; key = dist<<32 | (NN-idx): max
// key = max dist, tie -> max (NN-idx) = lowest idx = np.argmax. Within-thread
// ties: descending-j find, last write wins = lowest idx. DPP old=0 is the
// max-identity (keys > 0). Parity double-buffer on rkey (fast wave's iter+1
// write vs slow wave's iter read race).
// ---------------------------------------------------------------------------
__global__ __attribute__((amdgpu_flat_work_group_size(512, 512),
                          amdgpu_waves_per_eu(2, 2)))
void k_fps(const float* __restrict__ xyz, float* __restrict__ out_kp) {
  __shared__ float sxyz[NN * 3];  // [idx][x,y,z]
  __shared__ int sIdx[SS];
  __shared__ u64 rkey[2][8];
  int b = blockIdx.x, t = threadIdx.x;
  const float* base = xyz + b * N3;
  v2f px[8], py[8], pz[8], dm[8];
#pragma unroll
  for (int j = 0; j < 8; ++j) {
    int n0 = j * 1024 + t, n1 = n0 + 512;  // coalesced, disjoint cover [0,8192)
    px[j] = v2f{base[n0], base[n1]};
    py[j] = v2f{base[NN + n0], base[NN + n1]};
    pz[j] = v2f{base[2 * NN + n0], base[2 * NN + n1]};
    dm[j] = v2f{1e10f, 1e10f};
    sxyz[n0 * 3 + 0] = px[j].x;  // stage AoS copy for center re-loads
    sxyz[n0 * 3 + 1] = py[j].x;
    sxyz[n0 * 3 + 2] = pz[j].x;
    sxyz[n1 * 3 + 0] = px[j].y;
    sxyz[n1 * 3 + 1] = py[j].y;
    sxyz[n1 * 3 + 2] = pz[j].y;
  }
#pragma unroll
  for (int j = 0; j < 8; ++j) {
    // Opaque def: blocks rematerialization of the global loads.
    asm volatile("" : "+v"(px[j]), "+v"(py[j]), "+v"(pz[j]));
  }
  // staging writes become visible at iter-0's barrier, before first LDS read
  float cx = base[0], cy = base[NN], cz = base[2 * NN];
  int far = 0;
  int lane = t & 63, w = t >> 6;
  u32 tb = (u32)(NN - t);  // candidate base: cand = NN - gidx (1..8192; 0=none)
  for (int it = 0; it < SS; ++it) {
    if (t == 0) sIdx[it] = far;  // scan emits carry BEFORE update: idx[0]=0
    // negated center, broadcast to both halves (a + (-c) == a - c exactly)
    v2f ncx = v2f{-cx, -cx}, ncy = v2f{-cy, -cy}, ncz = v2f{-cz, -cz};
    float vmax = 0.0f;
#pragma unroll
    for (int j = 0; j < 8; ++j) {
      v2f dx = pk_add(px[j], ncx);
      v2f dy = pk_add(py[j], ncy);
      v2f dz = pk_add(pz[j], ncz);
      v2f xx = pk_mul(dx, dx);
      v2f yy = pk_mul(dy, dy);
      v2f s = pk_add(xx, yy);
      v2f zz = pk_mul(dz, dz);
      v2f d = pk_add(s, zz);  // ((dx^2+dy^2)+dz^2), numpy tree per half
      float a0 = fminf(dm[j].x, d.x);
      float a1 = fminf(dm[j].y, d.y);
      dm[j].x = a0;
      dm[j].y = a1;
      vmax = fmaxf(vmax, fmaxf(a0, a1));  // max3-foldable
    }
    // thread-local find vs this thread's OWN max: exact bit-equality (vmax IS
    // one of this thread's dm values). Descending gidx order -> LAST write =
    // lowest gidx within the thread.
    u32 cand = 0;
#pragma unroll
    for (int j = 7; j >= 0; --j) {
      u32 v1 = tb - (u32)(j * 1024 + 512);  // cand for .y half (higher gidx)
      u32 v0 = tb - (u32)(j * 1024);        // cand for .x half
      cand = (dm[j].y == vmax) ? v1 : cand;
      cand = (dm[j].x == vmax) ? v0 : cand;
    }
    // one packed key per thread; 6-step DPP u64 max chain -> lane63 holds the
    // wave best (max dist, tie -> max cand = min gidx). VALU pipe only.
    u64 key = ((u64)__float_as_uint(vmax) << 32) | cand;
    key = dpp_maxk<0x111>(key);  // row_shr:1
    key = dpp_maxk<0x112>(key);  // row_shr:2
    key = dpp_maxk<0x114>(key);  // row_shr:4
    key = dpp_maxk<0x118>(key);  // row_shr:8
    key = dpp_maxk<0x142>(key);  // row_bcast:15
    key = dpp_maxk<0x143>(key);  // row_bcast:31 -> lane63 = wave max
    int pb = it & 1;  // parity double-buffer: safe with one barrier/iter
    if (lane == 63) rkey[pb][w] = key;
    __syncthreads();  // the only barrier per iteration
    // block reduce over 8 wave keys: every thread broadcast-reads all 8 slots
    // (one pipelined LDS round trip, all-lane-same-addr) + redundant VALU
    // tree. No cross-lane ops at all in this phase.
    u64 k0 = rkey[pb][0], k1 = rkey[pb][1];
    u64 k2 = rkey[pb][2], k3 = rkey[pb][3];
    u64 k4 = rkey[pb][4], k5 = rkey[pb][5];
    u64 k6 = rkey[pb][6], k7 = rkey[pb][7];
    u64 kg = maxk(maxk(maxk(k0, k1), maxk(k2, k3)),
                  maxk(maxk(k4, k5), maxk(k6, k7)));
    far = NN - (int)(u32)(kg & 0xffffffffu);
    // broadcast ds_read of the winner's coords (all lanes same address,
    // 3 consecutive dwords)
    cx = sxyz[far * 3 + 0];
    cy = sxyz[far * 3 + 1];
    cz = sxyz[far * 3 + 2];
  }
  __syncthreads();
  for (int i = t; i < SS; i += 512) {
    int id = sIdx[i];
    out_kp[b * 1536 + i] = base[id];  // exact fp32 copies
    out_kp[b * 1536 + SS + i] = base[NN + id];
    out_kp[b * 1536 + 2 * SS + i] = base[2 * NN + id];
  }
}

// ---------------------------------------------------------------------------
// K2: per (b,s) row, sorted top-24 nearest (dist asc, idx asc) — prefixes give
// K=8/16/24 and base K=16 (lax.top_k stable tie-break). One wave per row.
// KD=14 per-lane depth (r11 win: non-fps time 634 -> 466 us): top-24 indices
// are ~uniform mod 64, P(any lane holds >=15 of 24) < 1e-15 over all rows.
// d = (|a|^2+|q|^2) - 2*dot, all rn ops, matching the numpy expression tree.
// ---------------------------------------------------------------------------
__global__ __launch_bounds__(256) void k_knn(const float* __restrict__ xyz,
                                             const float* __restrict__ kp,
                                             u16* __restrict__ knn) {
  int t = threadIdx.x;
  int row = blockIdx.x * 4 + (t >> 6);
  int lane = t & 63;
  int b = row >> 9, s = row & (SS - 1);
  const float* base = xyz + b * N3;
  float ax = kp[b * 1536 + s];
  float ay = kp[b * 1536 + SS + s];
  float az = kp[b * 1536 + 2 * SS + s];
  float aw = __fadd_rn(__fadd_rn(__fmul_rn(ax, ax), __fmul_rn(ay, ay)), __fmul_rn(az, az));
  u64 arr[KD];
#pragma unroll
  for (int i = 0; i < KD; ++i) arr[i] = ~0ull;
  for (int c = 0; c < 128; ++c) {
    int n = c * 64 + lane;
    float qx = base[n], qy = base[NN + n], qz = base[2 * NN + n];
    float qw = __fadd_rn(__fadd_rn(__fmul_rn(qx, qx), __fmul_rn(qy, qy)), __fmul_rn(qz, qz));
    float dot = __fadd_rn(__fadd_rn(__fmul_rn(ax, qx), __fmul_rn(ay, qy)), __fmul_rn(az, qz));
    float d = __fsub_rn(__fadd_rn(aw, qw), __fmul_rn(2.0f, dot));
    u32 ub = __float_as_uint(d);
    ub ^= (ub & 0x80000000u) ? 0xFFFFFFFFu : 0x80000000u;  // order-preserving map
    u64 key = ((u64)ub << 32) | (u32)n;
    if (key < arr[KD - 1]) {  // branchless descending insertion (arr asc)
#pragma unroll
      for (int i = KD - 1; i >= 1; --i) {
        u64 am = arr[i - 1];
        arr[i] = (am > key) ? am : ((arr[i] > key) ? key : arr[i]);
      }
      if (arr[0] > key) arr[0] = key;
    }
  }
  // merge 64 sorted lists: 24 x (wave-min of heads, winner pops). keys unique.
  u64 mine = 0;
  for (int it = 0; it < 24; ++it) {
    u64 m = arr[0];
#pragma unroll
    for (int off = 1; off < 64; off <<= 1) {
      u64 o = __shfl_xor(m, off, 64);
      m = (o < m) ? o : m;
    }
    if (lane == it) mine = m;
    if (arr[0] == m) {
#pragma unroll
      for (int i = 0; i < KD - 1; ++i) arr[i] = arr[i + 1];
      arr[KD - 1] = ~0ull;
    }
  }
  if (lane < 24) knn[row * 24 + lane] = (u16)(mine & 0xFFFFu);
}

// ---------------------------------------------------------------------------
// K3: base SA MLP. feat[16][6] = [rel_xyz | pts]; 6->64 relu -> 64->128; max
// over K=16. Wave = one row; each thread owns 2 output channels (lane,
// lane+64) with W2 rows in registers; h1 read as explicit float4 broadcast.
// Block = 4 rows in flight x 2 groups = 8 rows.
// ---------------------------------------------------------------------------
__global__ __launch_bounds__(256) void k_base(
    const float* __restrict__ xyz, const float* __restrict__ pts,
    const float* __restrict__ kp, const u16* __restrict__ knn,
    const float* __restrict__ W1, const float* __restrict__ b1,
    const float* __restrict__ W2, const float* __restrict__ b2,
    float* __restrict__ out) {
  __shared__ float sW1T[6 * 64];     // [c][o]
  __shared__ float sb1[64];
  __shared__ float sfeat[4][16 * 6]; // [row][k*6+c]
  __shared__ float sh1[4][16 * 64];  // [row][k*64+o]
  int t = threadIdx.x, lane = t & 63, w = t >> 6;
  int b = blockIdx.x >> 6, s0 = (blockIdx.x & 63) * 8;
  for (int i = t; i < 384; i += 256) {
    int o = i / 6, c = i - o * 6;
    sW1T[c * 64 + o] = W1[i];
  }
  if (t < 64) sb1[t] = b1[t];
  float wgtA[64], wgtB[64];
#pragma unroll
  for (int j = 0; j < 64; ++j) {
    wgtA[j] = W2[lane * 64 + j];
    wgtB[j] = W2[(lane + 64) * 64 + j];
  }
  float b2A = b2[lane], b2B = b2[lane + 64];
  __syncthreads();
  for (int g = 0; g < 2; ++g) {
    for (int i = t; i < 384; i += 256) {  // 4 rows x 16 k x 6 c
      int rr = i / 96, rem = i - rr * 96, k = rem / 6, c = rem - k * 6;
      int s = s0 + g * 4 + rr, row = b * SS + s;
      int id = knn[row * 24 + k];  // first 16 of sorted top-24 = base KNN
      float val;
      if (c < 3) {
        val = __fsub_rn(xyz[b * N3 + c * NN + id], kp[b * 1536 + c * SS + s]);
      } else {
        val = pts[b * N3 + (c - 3) * NN + id];
      }
      sfeat[rr][k * 6 + c] = val;
    }
    __syncthreads();
#pragma unroll
    for (int m = 0; m < 16; ++m) {  // 4 rows x 1024 h1 entries / 256 thr
      int u = m * 256 + t;
      int rr = u >> 10, rem = u & 1023, k = rem >> 6, o = rem & 63;
      float acc = sb1[o];
#pragma unroll
      for (int c = 0; c < 6; ++c) acc = fmaf(sfeat[rr][k * 6 + c], sW1T[c * 64 + o], acc);
      sh1[rr][k * 64 + o] = fmaxf(acc, 0.f);
    }
    __syncthreads();
    float bestA = -1e30f, bestB = -1e30f;
#pragma unroll
    for (int k = 0; k < 16; ++k) {
      const float4* h4 = (const float4*)&sh1[w][k * 64];  // wave-uniform bcast
      float a0 = 0.f, a1 = 0.f;
#pragma unroll
      for (int j = 0; j < 16; ++j) {
        float4 hv = h4[j];
        a0 = fmaf(hv.x, wgtA[4 * j], a0);
        a0 = fmaf(hv.y, wgtA[4 * j + 1], a0);
        a0 = fmaf(hv.z, wgtA[4 * j + 2], a0);
        a0 = fmaf(hv.w, wgtA[4 * j + 3], a0);
        a1 = fmaf(hv.x, wgtB[4 * j], a1);
        a1 = fmaf(hv.y, wgtB[4 * j + 1], a1);
        a1 = fmaf(hv.z, wgtB[4 * j + 2], a1);
        a1 = fmaf(hv.w, wgtB[4 * j + 3], a1);
      }
      bestA = fmaxf(bestA, a0);
      bestB = fmaxf(bestB, a1);
    }
    int s = s0 + g * 4 + w;
    out[24576 + b * 262144 + lane * 512 + s] = bestA + b2A;
    out[24576 + b * 262144 + (lane + 64) * 512 + s] = bestB + b2B;
    __syncthreads();  // protect sfeat/sh1 before next group overwrites
  }
}

// ---------------------------------------------------------------------------
// K4: multi-scale MLPs, scale = blockIdx.y, K = 8*(scale+1), rel-xyz only.
// Same 2-channels-per-thread structure. Output channels 128*(scale+1)..+128.
// ---------------------------------------------------------------------------
__global__ __launch_bounds__(256) void k_ms(
    const float* __restrict__ xyz, const float* __restrict__ kp,
    const u16* __restrict__ knn, const float* __restrict__ msW1,
    const float* __restrict__ msb1, const float* __restrict__ msW2,
    const float* __restrict__ msb2, float* __restrict__ out) {
  int scale = blockIdx.y;
  int kk = 8 * (scale + 1);
  __shared__ float sW1T[3 * 64];
  __shared__ float sb1[64];
  __shared__ float sfeat[4][24 * 3];
  __shared__ float sh1[4][24 * 64];
  int t = threadIdx.x, lane = t & 63, w = t >> 6;
  int b = blockIdx.x >> 6, s0 = (blockIdx.x & 63) * 8;
  const float* W1s = msW1 + scale * 192;
  for (int i = t; i < 192; i += 256) {
    int o = i / 3, c = i - o * 3;
    sW1T[c * 64 + o] = W1s[i];
  }
  if (t < 64) sb1[t] = msb1[scale * 64 + t];
  float wgtA[64], wgtB[64];
#pragma unroll
  for (int j = 0; j < 64; ++j) {
    wgtA[j] = msW2[scale * 8192 + lane * 64 + j];
    wgtB[j] = msW2[scale * 8192 + (lane + 64) * 64 + j];
  }
  float b2A = msb2[scale * 128 + lane], b2B = msb2[scale * 128 + lane + 64];
  __syncthreads();
  int co = 128 * (scale + 1);
  for (int g = 0; g < 2; ++g) {
    int nfeat = 4 * kk * 3;
    for (int i = t; i < nfeat; i += 256) {  // 4 rows x kk k x 3 c
      int kk3 = kk * 3;
      int rr = i / kk3, rem = i - rr * kk3, k = rem / 3, c = rem - k * 3;
      int s = s0 + g * 4 + rr, row = b * SS + s;
      int id = knn[row * 24 + k];
      sfeat[rr][k * 3 + c] = __fsub_rn(xyz[b * N3 + c * NN + id], kp[b * 1536 + c * SS + s]);
    }
    __syncthreads();
    for (int rr = 0; rr < 4; ++rr) {  // h1 for kk*64 entries per row
      for (int u = t; u < kk * 64; u += 256) {
        int k = u >> 6, o = u & 63;
        float acc = sb1[o];
        acc = fmaf(sfeat[rr][k * 3 + 0], sW1T[o], acc);
        acc = fmaf(sfeat[rr][k * 3 + 1], sW1T[64 + o], acc);
        acc = fmaf(sfeat[rr][k * 3 + 2], sW1T[128 + o], acc);
        sh1[rr][k * 64 + o] = fmaxf(acc, 0.f);
      }
    }
    __syncthreads();
    float bestA = -1e30f, bestB = -1e30f;
    for (int k = 0; k < kk; ++k) {  // kk uniform across block -> no divergence
      const float4* h4 = (const float4*)&sh1[w][k * 64];
      float a0 = 0.f, a1 = 0.f;
#pragma unroll
      for (int j = 0; j < 16; ++j) {
        float4 hv = h4[j];
        a0 = fmaf(hv.x, wgtA[4 * j], a0);
        a0 = fmaf(hv.y, wgtA[4 * j + 1], a0);
        a0 = fmaf(hv.z, wgtA[4 * j + 2], a0);
        a0 = fmaf(hv.w, wgtA[4 * j + 3], a0);
        a1 = fmaf(hv.x, wgtB[4 * j], a1);
        a1 = fmaf(hv.y, wgtB[4 * j + 1], a1);
        a1 = fmaf(hv.z, wgtB[4 * j + 2], a1);
        a1 = fmaf(hv.w, wgtB[4 * j + 3], a1);
      }
      bestA = fmaxf(bestA, a0);
      bestB = fmaxf(bestB, a1);
    }
    int s = s0 + g * 4 + w;
    out[24576 + b * 262144 + (co + lane) * 512 + s] = bestA + b2A;
    out[24576 + b * 262144 + (co + lane + 64) * 512 + s] = bestB + b2B;
    __syncthreads();
  }
}

// ---------------------------------------------------------------------------
extern "C" void kernel_launch(void* const* d_in, const int* in_sizes, int n_in,
                              void* d_out, int out_size, void* d_ws, size_t ws_size,
                              hipStream_t stream) {
  const float* xyz = (const float*)d_in[0];    // l0_xyz  [B,3,N] f32
  const float* pts = (const float*)d_in[1];    // l0_points
  const float* sa_W1 = (const float*)d_in[2];  // [64,6]
  const float* sa_b1 = (const float*)d_in[3];  // [64]
  const float* sa_W2 = (const float*)d_in[4];  // [128,64]
  const float* sa_b2 = (const float*)d_in[5];  // [128]
  const float* ms_W1 = (const float*)d_in[6];  // [3,64,3]
  const float* ms_b1 = (const float*)d_in[7];  // [3,64]
  const float* ms_W2 = (const float*)d_in[8];  // [3,128,64]
  const float* ms_b2 = (const float*)d_in[9];  // [3,128]
  float* out = (float*)d_out;
  const float* kp = (const float*)d_out;  // keypoints written by k_fps

  // workspace: knn u16[B*S*24] = 384 KB
  u16* knn = (u16*)d_ws;

  k_fps<<<BB, 512, 0, stream>>>(xyz, out);
  k_knn<<<(BB * SS) / 4, 256, 0, stream>>>(xyz, kp, knn);
  k_base<<<BB * 64, 256, 0, stream>>>(xyz, pts, kp, knn, sa_W1, sa_b1, sa_W2, sa_b2, out);
  k_ms<<<dim3(BB * 64, 3), 256, 0, stream>>>(xyz, kp, knn, ms_W1, ms_b1, ms_W2, ms_b2, out);
}

// Round 4
// 967.058 us; speedup vs baseline: 1.1931x; 1.0391x over previous
//
#include <hip/hip_runtime.h>

#define BB 16
#define NN 8192
#define SS 512
#define N3 (3 * NN)  // 24576 elements per batch per tensor
#define KD 14        // per-lane KNN list depth (see k_knn comment)

typedef unsigned short u16;
typedef unsigned int u32;
typedef unsigned long long u64;
typedef float v2f __attribute__((ext_vector_type(2)));

// Packed fp32 ops (VOP3P, 2 points/inst). Per-half rounding is IEEE rn —
// bit-identical to scalar __fadd_rn/__fmul_rn.
__device__ __forceinline__ v2f pk_add(v2f a, v2f b) {
  v2f r;
  asm("v_pk_add_f32 %0, %1, %2" : "=v"(r) : "v"(a), "v"(b));
  return r;
}
__device__ __forceinline__ v2f pk_mul(v2f a, v2f b) {
  v2f r;
  asm("v_pk_mul_f32 %0, %1, %2" : "=v"(r) : "v"(a), "v"(b));
  return r;
}

// u64 max step over a DPP lane-shift: shift both 32-bit halves with the same
// control (old=0 is the identity for max of our non-negative keys), then one
// v_cmp_lt_u64 + 2 cndmask. Stays entirely on the VALU pipe — r15's lesson:
// __shfl_xor is ds_bpermute (LDS pipe, ~40+cy dependent) and 9 such steps on
// the serial path cost ~+500cy/iter (544 -> 658 us).
template <int CTRL>
__device__ __forceinline__ u64 dpp_maxk(u64 k) {
  u32 lo = (u32)k, hi = (u32)(k >> 32);
  u32 slo = (u32)__builtin_amdgcn_update_dpp(0, (int)lo, CTRL, 0xf, 0xf, false);
  u32 shi = (u32)__builtin_amdgcn_update_dpp(0, (int)hi, CTRL, 0xf, 0xf, false);
  u64 s = ((u64)shi << 32) | (u64)slo;
  return (s > k) ? s : k;
}
__device__ __forceinline__ u64 maxk(u64 a, u64 b) { return (a > b) ? a : b; }

// ---------------------------------------------------------------------------
// K0 (r17 new): precompute per-point float4 {x,y,z,|q|^2} for xyz and
// {x,y,z,0} for l0_points into workspace. |q|^2 uses the EXACT rn tree k_knn
// used in-loop, so downstream bits are unchanged. ~4 MB writes, ~4 us.
// Purpose: k_knn main loop drops from 3 scattered-stream dword loads + 5 VALU
// to ONE dwordx4 load; k_mlp staging gathers drop 3-6 dwords -> 1-2 dwordx4.
// ---------------------------------------------------------------------------
__global__ __launch_bounds__(256) void k_prep(const float* __restrict__ xyz,
                                              const float* __restrict__ pts,
                                              float4* __restrict__ xyz4,
                                              float4* __restrict__ pts4) {
  int i = blockIdx.x * 256 + threadIdx.x;  // < BB*NN
  int b = i >> 13, n = i & (NN - 1);
  const float* xb = xyz + b * N3;
  float x = xb[n], y = xb[NN + n], z = xb[2 * NN + n];
  float w = __fadd_rn(__fadd_rn(__fmul_rn(x, x), __fmul_rn(y, y)), __fmul_rn(z, z));
  xyz4[i] = make_float4(x, y, z, w);
  const float* pb = pts + b * N3;
  pts4[i] = make_float4(pb[n], pb[NN + n], pb[2 * NN + n], 0.f);
}

// ---------------------------------------------------------------------------
// K1: farthest point sampling, fp32, bit-exact vs numpy. r16 structure kept
// UNCHANGED in r17 (510us, VALUBusy ~78% of 16-CU cap — near issue-bound).
// History: r13 256thr 544us latency-bound; r14 1024thr 661us (4x per-wave
// overhead); r15 512thr+shfl 658us (shfl = ds_bpermute LDS latency);
// r16 512thr, all cross-lane on the VALU pipe: thread-local find vs OWN vmax
// -> ONE u64 DPP max chain -> lane63 ds_write -> ONE barrier -> broadcast
// read of 8 wave keys + redundant VALU tree -> broadcast coords read.
// Exactness: vmax is bit-identical to one of this thread's dm values; d >= +0
// so float bits are order-preserving as u32; key = dist<<32 | (NN-idx): max
// key = max dist, tie -> max (NN-idx) = lowest idx = np.argmax. Within-thread
// ties: descending-j find, last write wins = lowest idx. DPP old=0 is the
// max-identity (keys > 0). Parity double-buffer on rkey.
// ---------------------------------------------------------------------------
__global__ __attribute__((amdgpu_flat_work_group_size(512, 512),
                          amdgpu_waves_per_eu(2, 2)))
void k_fps(const float* __restrict__ xyz, float* __restrict__ out_kp) {
  __shared__ float sxyz[NN * 3];  // [idx][x,y,z]
  __shared__ int sIdx[SS];
  __shared__ u64 rkey[2][8];
  int b = blockIdx.x, t = threadIdx.x;
  const float* base = xyz + b * N3;
  v2f px[8], py[8], pz[8], dm[8];
#pragma unroll
  for (int j = 0; j < 8; ++j) {
    int n0 = j * 1024 + t, n1 = n0 + 512;  // coalesced, disjoint cover [0,8192)
    px[j] = v2f{base[n0], base[n1]};
    py[j] = v2f{base[NN + n0], base[NN + n1]};
    pz[j] = v2f{base[2 * NN + n0], base[2 * NN + n1]};
    dm[j] = v2f{1e10f, 1e10f};
    sxyz[n0 * 3 + 0] = px[j].x;  // stage AoS copy for center re-loads
    sxyz[n0 * 3 + 1] = py[j].x;
    sxyz[n0 * 3 + 2] = pz[j].x;
    sxyz[n1 * 3 + 0] = px[j].y;
    sxyz[n1 * 3 + 1] = py[j].y;
    sxyz[n1 * 3 + 2] = pz[j].y;
  }
#pragma unroll
  for (int j = 0; j < 8; ++j) {
    // Opaque def: blocks rematerialization of the global loads.
    asm volatile("" : "+v"(px[j]), "+v"(py[j]), "+v"(pz[j]));
  }
  // staging writes become visible at iter-0's barrier, before first LDS read
  float cx = base[0], cy = base[NN], cz = base[2 * NN];
  int far = 0;
  int lane = t & 63, w = t >> 6;
  u32 tb = (u32)(NN - t);  // candidate base: cand = NN - gidx (1..8192; 0=none)
  for (int it = 0; it < SS; ++it) {
    if (t == 0) sIdx[it] = far;  // scan emits carry BEFORE update: idx[0]=0
    // negated center, broadcast to both halves (a + (-c) == a - c exactly)
    v2f ncx = v2f{-cx, -cx}, ncy = v2f{-cy, -cy}, ncz = v2f{-cz, -cz};
    float vmax = 0.0f;
#pragma unroll
    for (int j = 0; j < 8; ++j) {
      v2f dx = pk_add(px[j], ncx);
      v2f dy = pk_add(py[j], ncy);
      v2f dz = pk_add(pz[j], ncz);
      v2f xx = pk_mul(dx, dx);
      v2f yy = pk_mul(dy, dy);
      v2f s = pk_add(xx, yy);
      v2f zz = pk_mul(dz, dz);
      v2f d = pk_add(s, zz);  // ((dx^2+dy^2)+dz^2), numpy tree per half
      float a0 = fminf(dm[j].x, d.x);
      float a1 = fminf(dm[j].y, d.y);
      dm[j].x = a0;
      dm[j].y = a1;
      vmax = fmaxf(vmax, fmaxf(a0, a1));  // max3-foldable
    }
    // thread-local find vs this thread's OWN max: exact bit-equality (vmax IS
    // one of this thread's dm values). Descending gidx order -> LAST write =
    // lowest gidx within the thread.
    u32 cand = 0;
#pragma unroll
    for (int j = 7; j >= 0; --j) {
      u32 v1 = tb - (u32)(j * 1024 + 512);  // cand for .y half (higher gidx)
      u32 v0 = tb - (u32)(j * 1024);        // cand for .x half
      cand = (dm[j].y == vmax) ? v1 : cand;
      cand = (dm[j].x == vmax) ? v0 : cand;
    }
    // one packed key per thread; 6-step DPP u64 max chain -> lane63 holds the
    // wave best (max dist, tie -> max cand = min gidx). VALU pipe only.
    u64 key = ((u64)__float_as_uint(vmax) << 32) | cand;
    key = dpp_maxk<0x111>(key);  // row_shr:1
    key = dpp_maxk<0x112>(key);  // row_shr:2
    key = dpp_maxk<0x114>(key);  // row_shr:4
    key = dpp_maxk<0x118>(key);  // row_shr:8
    key = dpp_maxk<0x142>(key);  // row_bcast:15
    key = dpp_maxk<0x143>(key);  // row_bcast:31 -> lane63 = wave max
    int pb = it & 1;  // parity double-buffer: safe with one barrier/iter
    if (lane == 63) rkey[pb][w] = key;
    __syncthreads();  // the only barrier per iteration
    // block reduce over 8 wave keys: every thread broadcast-reads all 8 slots
    // (one pipelined LDS round trip, all-lane-same-addr) + redundant VALU
    // tree. No cross-lane ops at all in this phase.
    u64 k0 = rkey[pb][0], k1 = rkey[pb][1];
    u64 k2 = rkey[pb][2], k3 = rkey[pb][3];
    u64 k4 = rkey[pb][4], k5 = rkey[pb][5];
    u64 k6 = rkey[pb][6], k7 = rkey[pb][7];
    u64 kg = maxk(maxk(maxk(k0, k1), maxk(k2, k3)),
                  maxk(maxk(k4, k5), maxk(k6, k7)));
    far = NN - (int)(u32)(kg & 0xffffffffu);
    // broadcast ds_read of the winner's coords (all lanes same address,
    // 3 consecutive dwords)
    cx = sxyz[far * 3 + 0];
    cy = sxyz[far * 3 + 1];
    cz = sxyz[far * 3 + 2];
  }
  __syncthreads();
  for (int i = t; i < SS; i += 512) {
    int id = sIdx[i];
    out_kp[b * 1536 + i] = base[id];  // exact fp32 copies
    out_kp[b * 1536 + SS + i] = base[NN + id];
    out_kp[b * 1536 + 2 * SS + i] = base[2 * NN + id];
  }
}

// ---------------------------------------------------------------------------
// K2: per (b,s) row, sorted top-24 nearest (dist asc, idx asc) — prefixes give
// K=8/16/24 and base K=16 (lax.top_k stable tie-break). One wave per row.
// KD=14 per-lane depth (r11 win): top-24 indices ~uniform mod 64, P(any lane
// holds >=15 of 24) < 1e-15 over all rows.
// r17: USE4 path loads ONE float4 {x,y,z,|q|^2} per chunk (replaces 3
// scattered-stream dword loads + 5 VALU for qw — ~30% of the non-insert
// loop); insertion uses explicitly CSE'd conditions (14 u64 cmps + selects).
// d = (|a|^2+|q|^2) - 2*dot, all rn ops, matching the numpy expression tree;
// prep's |q|^2 uses the identical tree -> bit-identical d.
// ---------------------------------------------------------------------------
template <int USE4>
__global__ __launch_bounds__(256) void k_knn(const float* __restrict__ xyz,
                                             const float4* __restrict__ xyz4,
                                             const float* __restrict__ kp,
                                             u16* __restrict__ knn) {
  int t = threadIdx.x;
  int row = blockIdx.x * 4 + (t >> 6);
  int lane = t & 63;
  int b = row >> 9, s = row & (SS - 1);
  const float* base = xyz + b * N3;
  const float4* base4 = xyz4 + (b << 13);
  float ax = kp[b * 1536 + s];
  float ay = kp[b * 1536 + SS + s];
  float az = kp[b * 1536 + 2 * SS + s];
  float aw = __fadd_rn(__fadd_rn(__fmul_rn(ax, ax), __fmul_rn(ay, ay)), __fmul_rn(az, az));
  u64 arr[KD];
#pragma unroll
  for (int i = 0; i < KD; ++i) arr[i] = ~0ull;
  for (int c = 0; c < 128; ++c) {
    int n = c * 64 + lane;
    float qx, qy, qz, qw;
    if constexpr (USE4) {
      float4 q = base4[n];  // one dwordx4, coalesced
      qx = q.x; qy = q.y; qz = q.z; qw = q.w;
    } else {
      qx = base[n]; qy = base[NN + n]; qz = base[2 * NN + n];
      qw = __fadd_rn(__fadd_rn(__fmul_rn(qx, qx), __fmul_rn(qy, qy)), __fmul_rn(qz, qz));
    }
    float dot = __fadd_rn(__fadd_rn(__fmul_rn(ax, qx), __fmul_rn(ay, qy)), __fmul_rn(az, qz));
    float d = __fsub_rn(__fadd_rn(aw, qw), __fmul_rn(2.0f, dot));
    u32 ub = __float_as_uint(d);
    ub ^= (ub & 0x80000000u) ? 0xFFFFFFFFu : 0x80000000u;  // order-preserving map
    u64 key = ((u64)ub << 32) | (u32)n;
    if (key < arr[KD - 1]) {  // sorted insert, conditions CSE'd explicitly
      bool cg[KD];
#pragma unroll
      for (int i = 0; i < KD; ++i) cg[i] = arr[i] > key;
#pragma unroll
      for (int i = KD - 1; i >= 1; --i)
        arr[i] = cg[i - 1] ? arr[i - 1] : (cg[i] ? key : arr[i]);
      arr[0] = cg[0] ? key : arr[0];
    }
  }
  // merge 64 sorted lists: 24 x (wave-min of heads, winner pops). keys unique.
  u64 mine = 0;
  for (int it = 0; it < 24; ++it) {
    u64 m = arr[0];
#pragma unroll
    for (int off = 1; off < 64; off <<= 1) {
      u64 o = __shfl_xor(m, off, 64);
      m = (o < m) ? o : m;
    }
    if (lane == it) mine = m;
    if (arr[0] == m) {
#pragma unroll
      for (int i = 0; i < KD - 1; ++i) arr[i] = arr[i + 1];
      arr[KD - 1] = ~0ull;
    }
  }
  if (lane < 24) knn[row * 24 + lane] = (u16)(mine & 0xFFFFu);
}

// ---------------------------------------------------------------------------
// K3 (r17): fused base-SA + multi-scale MLPs in ONE launch. blockIdx.y = 0 ->
// base (feat [rel_xyz|pts] 6->64 relu -> 64->128, K=16, out ch 0..127);
// blockIdx.y = 1..3 -> ms scale y-1 (rel_xyz 3->64 relu -> 64->128, K=8y,
// out ch 128y..128y+127). Fusion overlaps the two former kernels (removes a
// serialization boundary + tail bubble). Branch is block-uniform.
// Shared LDS carve-out: max(base 4928, ms 6688) floats. Staging gathers via
// float4 (USE4) — 1-2 dwordx4 per (row,k) vs 3-6 scattered dwords — and the
// old runtime-division (i/kk3) staging map is gone (constant /24 only).
// Per-wave h2 structure unchanged: thread owns 2 out channels, W2 rows in
// registers, h1 read as wave-uniform float4 broadcast.
// ---------------------------------------------------------------------------
template <int USE4>
__global__ __launch_bounds__(256) void k_mlp(
    const float* __restrict__ xyz, const float* __restrict__ pts,
    const float4* __restrict__ xyz4, const float4* __restrict__ pts4,
    const float* __restrict__ kp, const u16* __restrict__ knn,
    const float* __restrict__ W1, const float* __restrict__ b1,
    const float* __restrict__ W2, const float* __restrict__ b2,
    const float* __restrict__ msW1, const float* __restrict__ msb1,
    const float* __restrict__ msW2, const float* __restrict__ msb2,
    float* __restrict__ out) {
  __shared__ float smem[6688];
  int t = threadIdx.x, lane = t & 63, w = t >> 6;
  int b = blockIdx.x >> 6, s0 = (blockIdx.x & 63) * 8;
  if (blockIdx.y == 0) {
    // ---------------- base plane ----------------
    float* sW1T = smem;          // [c][o] 6*64
    float* sb1 = smem + 384;     // 64
    float* sfeat = smem + 448;   // [row][k*6+c] 4*96
    float* sh1 = smem + 832;     // [row][k*64+o] 4*1024 (16B-aligned: 3328B)
    for (int i = t; i < 384; i += 256) {
      int o = i / 6, c = i - o * 6;
      sW1T[c * 64 + o] = W1[i];
    }
    if (t < 64) sb1[t] = b1[t];
    float wgtA[64], wgtB[64];
#pragma unroll
    for (int j = 0; j < 64; ++j) {
      wgtA[j] = W2[lane * 64 + j];
      wgtB[j] = W2[(lane + 64) * 64 + j];
    }
    float b2A = b2[lane], b2B = b2[lane + 64];
    __syncthreads();
    for (int g = 0; g < 2; ++g) {
      if (t < 128) {  // 64 (rr,k) pairs x 2 halves: h=0 xyz, h=1 pts
        int p = t >> 1, h = t & 1;
        int rr = p >> 4, k = p & 15;
        int s = s0 + g * 4 + rr, row = b * SS + s;
        int id = knn[row * 24 + k];  // first 16 of sorted top-24 = base KNN
        float* f = &sfeat[rr * 96 + k * 6];
        if (h == 0) {
          float qx, qy, qz;
          if constexpr (USE4) {
            float4 q = xyz4[(b << 13) + id];
            qx = q.x; qy = q.y; qz = q.z;
          } else {
            qx = xyz[b * N3 + id];
            qy = xyz[b * N3 + NN + id];
            qz = xyz[b * N3 + 2 * NN + id];
          }
          f[0] = __fsub_rn(qx, kp[b * 1536 + s]);
          f[1] = __fsub_rn(qy, kp[b * 1536 + SS + s]);
          f[2] = __fsub_rn(qz, kp[b * 1536 + 2 * SS + s]);
        } else {
          float px_, py_, pz_;
          if constexpr (USE4) {
            float4 q = pts4[(b << 13) + id];
            px_ = q.x; py_ = q.y; pz_ = q.z;
          } else {
            px_ = pts[b * N3 + id];
            py_ = pts[b * N3 + NN + id];
            pz_ = pts[b * N3 + 2 * NN + id];
          }
          f[3] = px_;
          f[4] = py_;
          f[5] = pz_;
        }
      }
      __syncthreads();
#pragma unroll
      for (int m = 0; m < 16; ++m) {  // 4 rows x 1024 h1 entries / 256 thr
        int u = m * 256 + t;
        int rr = u >> 10, rem = u & 1023, k = rem >> 6, o = rem & 63;
        float acc = sb1[o];
#pragma unroll
        for (int c = 0; c < 6; ++c) acc = fmaf(sfeat[rr * 96 + k * 6 + c], sW1T[c * 64 + o], acc);
        sh1[rr * 1024 + k * 64 + o] = fmaxf(acc, 0.f);
      }
      __syncthreads();
      float bestA = -1e30f, bestB = -1e30f;
#pragma unroll
      for (int k = 0; k < 16; ++k) {
        const float4* h4 = (const float4*)&sh1[w * 1024 + k * 64];  // wave-uniform bcast
        float a0 = 0.f, a1 = 0.f;
#pragma unroll
        for (int j = 0; j < 16; ++j) {
          float4 hv = h4[j];
          a0 = fmaf(hv.x, wgtA[4 * j], a0);
          a0 = fmaf(hv.y, wgtA[4 * j + 1], a0);
          a0 = fmaf(hv.z, wgtA[4 * j + 2], a0);
          a0 = fmaf(hv.w, wgtA[4 * j + 3], a0);
          a1 = fmaf(hv.x, wgtB[4 * j], a1);
          a1 = fmaf(hv.y, wgtB[4 * j + 1], a1);
          a1 = fmaf(hv.z, wgtB[4 * j + 2], a1);
          a1 = fmaf(hv.w, wgtB[4 * j + 3], a1);
        }
        bestA = fmaxf(bestA, a0);
        bestB = fmaxf(bestB, a1);
      }
      int s = s0 + g * 4 + w;
      out[24576 + b * 262144 + lane * 512 + s] = bestA + b2A;
      out[24576 + b * 262144 + (lane + 64) * 512 + s] = bestB + b2B;
      __syncthreads();  // protect sfeat/sh1 before next group overwrites
    }
  } else {
    // ---------------- ms planes (scale = y-1, kk = 8*(scale+1)) ----------------
    int scale = blockIdx.y - 1;
    int kk = 8 * (scale + 1);
    float* sW1T = smem;          // [c][o] 3*64
    float* sb1 = smem + 192;     // 64
    float* sfeat = smem + 256;   // [row][k*3+c] 4*72
    float* sh1 = smem + 544;     // [row][k*64+o] 4*1536 (16B-aligned: 2176B)
    const float* W1s = msW1 + scale * 192;
    for (int i = t; i < 192; i += 256) {
      int o = i / 3, c = i - o * 3;
      sW1T[c * 64 + o] = W1s[i];
    }
    if (t < 64) sb1[t] = msb1[scale * 64 + t];
    float wgtA[64], wgtB[64];
#pragma unroll
    for (int j = 0; j < 64; ++j) {
      wgtA[j] = msW2[scale * 8192 + lane * 64 + j];
      wgtB[j] = msW2[scale * 8192 + (lane + 64) * 64 + j];
    }
    float b2A = msb2[scale * 128 + lane], b2B = msb2[scale * 128 + lane + 64];
    __syncthreads();
    int co = 128 * (scale + 1);
    for (int g = 0; g < 2; ++g) {
      if (t < 96) {  // 4 rows x 24 slots (stage all 24; h1 reads only k<kk)
        int rr = t / 24, k = t - rr * 24;  // constant divisor -> mul-shift
        int s = s0 + g * 4 + rr, row = b * SS + s;
        int id = knn[row * 24 + k];
        float qx, qy, qz;
        if constexpr (USE4) {
          float4 q = xyz4[(b << 13) + id];
          qx = q.x; qy = q.y; qz = q.z;
        } else {
          qx = xyz[b * N3 + id];
          qy = xyz[b * N3 + NN + id];
          qz = xyz[b * N3 + 2 * NN + id];
        }
        float* f = &sfeat[rr * 72 + k * 3];
        f[0] = __fsub_rn(qx, kp[b * 1536 + s]);
        f[1] = __fsub_rn(qy, kp[b * 1536 + SS + s]);
        f[2] = __fsub_rn(qz, kp[b * 1536 + 2 * SS + s]);
      }
      __syncthreads();
      for (int rr = 0; rr < 4; ++rr) {  // h1 for kk*64 entries per row
        for (int u = t; u < kk * 64; u += 256) {
          int k = u >> 6, o = u & 63;
          float acc = sb1[o];
          acc = fmaf(sfeat[rr * 72 + k * 3 + 0], sW1T[o], acc);
          acc = fmaf(sfeat[rr * 72 + k * 3 + 1], sW1T[64 + o], acc);
          acc = fmaf(sfeat[rr * 72 + k * 3 + 2], sW1T[128 + o], acc);
          sh1[rr * 1536 + k * 64 + o] = fmaxf(acc, 0.f);
        }
      }
      __syncthreads();
      float bestA = -1e30f, bestB = -1e30f;
      for (int k = 0; k < kk; ++k) {  // kk uniform across block -> no divergence
        const float4* h4 = (const float4*)&sh1[w * 1536 + k * 64];
        float a0 = 0.f, a1 = 0.f;
#pragma unroll
        for (int j = 0; j < 16; ++j) {
          float4 hv = h4[j];
          a0 = fmaf(hv.x, wgtA[4 * j], a0);
          a0 = fmaf(hv.y, wgtA[4 * j + 1], a0);
          a0 = fmaf(hv.z, wgtA[4 * j + 2], a0);
          a0 = fmaf(hv.w, wgtA[4 * j + 3], a0);
          a1 = fmaf(hv.x, wgtB[4 * j], a1);
          a1 = fmaf(hv.y, wgtB[4 * j + 1], a1);
          a1 = fmaf(hv.z, wgtB[4 * j + 2], a1);
          a1 = fmaf(hv.w, wgtB[4 * j + 3], a1);
        }
        bestA = fmaxf(bestA, a0);
        bestB = fmaxf(bestB, a1);
      }
      int s = s0 + g * 4 + w;
      out[24576 + b * 262144 + (co + lane) * 512 + s] = bestA + b2A;
      out[24576 + b * 262144 + (co + lane + 64) * 512 + s] = bestB + b2B;
      __syncthreads();
    }
  }
}

// ---------------------------------------------------------------------------
extern "C" void kernel_launch(void* const* d_in, const int* in_sizes, int n_in,
                              void* d_out, int out_size, void* d_ws, size_t ws_size,
                              hipStream_t stream) {
  const float* xyz = (const float*)d_in[0];    // l0_xyz  [B,3,N] f32
  const float* pts = (const float*)d_in[1];    // l0_points
  const float* sa_W1 = (const float*)d_in[2];  // [64,6]
  const float* sa_b1 = (const float*)d_in[3];  // [64]
  const float* sa_W2 = (const float*)d_in[4];  // [128,64]
  const float* sa_b2 = (const float*)d_in[5];  // [128]
  const float* ms_W1 = (const float*)d_in[6];  // [3,64,3]
  const float* ms_b1 = (const float*)d_in[7];  // [3,64]
  const float* ms_W2 = (const float*)d_in[8];  // [3,128,64]
  const float* ms_b2 = (const float*)d_in[9];  // [3,128]
  float* out = (float*)d_out;
  const float* kp = (const float*)d_out;  // keypoints written by k_fps

  // workspace: knn u16[B*S*24] = 393216 B, then xyz4/pts4 float4[B*N] = 2 MB each
  u16* knn = (u16*)d_ws;
  float4* xyz4 = (float4*)((char*)d_ws + 393216);
  float4* pts4 = xyz4 + BB * NN;
  const size_t need4 = 393216 + (size_t)2 * BB * NN * sizeof(float4);
  const bool use4 = ws_size >= need4;

  if (use4) k_prep<<<BB * NN / 256, 256, 0, stream>>>(xyz, pts, xyz4, pts4);
  k_fps<<<BB, 512, 0, stream>>>(xyz, out);
  if (use4) {
    k_knn<1><<<(BB * SS) / 4, 256, 0, stream>>>(xyz, xyz4, kp, knn);
    k_mlp<1><<<dim3(BB * 64, 4), 256, 0, stream>>>(xyz, pts, xyz4, pts4, kp, knn,
                                                   sa_W1, sa_b1, sa_W2, sa_b2,
                                                   ms_W1, ms_b1, ms_W2, ms_b2, out);
  } else {
    k_knn<0><<<(BB * SS) / 4, 256, 0, stream>>>(xyz, xyz4, kp, knn);
    k_mlp<0><<<dim3(BB * 64, 4), 256, 0, stream>>>(xyz, pts, xyz4, pts4, kp, knn,
                                                   sa_W1, sa_b1, sa_W2, sa_b2,
                                                   ms_W1, ms_b1, ms_W2, ms_b2, out);
  }
}